// Round 6
// baseline (354.715 us; speedup 1.0000x reference)
//
#include <hip/hip_runtime.h>

#define B_ 8
#define N_ 256
#define D_ 512
#define TI 4   // query rows per block

// ---------- Kernel 0: transpose k[b][j][d] -> kT[b][d][j] ----------
__global__ __launch_bounds__(256)
void transpose_k(const float* __restrict__ k, float* __restrict__ kT)
{
    __shared__ float tile[32][33];
    const int dt = blockIdx.x * 32;
    const int jt = blockIdx.y * 32;
    const int b  = blockIdx.z;
    const int tx = threadIdx.x;   // 0..31
    const int ty = threadIdx.y;   // 0..7

    const float* __restrict__ src = k  + ((size_t)b * N_) * D_;
    float* __restrict__       dst = kT + ((size_t)b * D_) * N_;

    #pragma unroll
    for (int r = 0; r < 4; ++r) {
        const int jj = ty * 4 + r;
        tile[jj][tx] = src[(size_t)(jt + jj) * D_ + dt + tx];
    }
    __syncthreads();
    #pragma unroll
    for (int r = 0; r < 4; ++r) {
        const int dd = ty * 4 + r;
        dst[(size_t)(dt + dd) * N_ + jt + tx] = tile[tx][dd];
    }
}

// ---------- Main kernel: TI=4, 512 threads (8 waves), grid = 512 ----------
// b = bid & 7 (batch-major XCD mapping), tile = bid >> 3.
// Phase A: wave w owns d-octant (64 d) x all 4 rows, double-buffered k loads.
// Phase C: thread owns (d-quad, j-quarter) x all 4 rows, double-buffered v.
__global__ __launch_bounds__(512, 4)
void manh_attn_v6(const float* __restrict__ q,
                  const float* __restrict__ kT,
                  const float* __restrict__ v,
                  float* __restrict__ out)
{
    __shared__ float s_q[TI * D_];       // 8 KB
    __shared__ float s_part[8 * 1024];   // 32 KB scratch (both reduces)
    __shared__ float s_w[TI * N_];       // 4 KB

    const int t  = threadIdx.x;
    const int b  = blockIdx.x & 7;          // batch -> XCD locality
    const int i0 = (blockIdx.x >> 3) * TI;  // 0..63 tiles

    // ---- stage q tile (4 rows x 512) into LDS, one float4 per thread ----
    {
        const float* __restrict__ qsrc = q + ((size_t)(b * N_ + i0)) * D_;
        *(float4*)&s_q[4 * t] = *(const float4*)(qsrc + 4 * t);
    }
    __syncthreads();

    const int lane = t & 63;
    const int w    = t >> 6;       // 0..7 = d-octant
    const int dlo  = w * 64;

    // ---- Phase A: partial L1 distances, software-pipelined k loads ----
    float4 acc0 = make_float4(0.f,0.f,0.f,0.f);
    float4 acc1 = make_float4(0.f,0.f,0.f,0.f);
    float4 acc2 = make_float4(0.f,0.f,0.f,0.f);
    float4 acc3 = make_float4(0.f,0.f,0.f,0.f);

    const float* __restrict__ kbase =
        kT + (size_t)b * D_ * N_ + (size_t)dlo * N_ + lane * 4;

    float4 kc0 = *(const float4*)(kbase);
    float4 kc1 = *(const float4*)(kbase + N_);
    float4 kc2 = *(const float4*)(kbase + 2 * N_);
    float4 kc3 = *(const float4*)(kbase + 3 * N_);

#define ACC4(A, QP)                                                            \
    {                                                                          \
        const float4 q4 = *(const float4*)(QP);                                \
        A.x += (fabsf(q4.x - kc0.x) + fabsf(q4.y - kc1.x)) +                   \
               (fabsf(q4.z - kc2.x) + fabsf(q4.w - kc3.x));                    \
        A.y += (fabsf(q4.x - kc0.y) + fabsf(q4.y - kc1.y)) +                   \
               (fabsf(q4.z - kc2.y) + fabsf(q4.w - kc3.y));                    \
        A.z += (fabsf(q4.x - kc0.z) + fabsf(q4.y - kc1.z)) +                   \
               (fabsf(q4.z - kc2.z) + fabsf(q4.w - kc3.z));                    \
        A.w += (fabsf(q4.x - kc0.w) + fabsf(q4.y - kc1.w)) +                   \
               (fabsf(q4.z - kc2.w) + fabsf(q4.w - kc3.w));                    \
    }

    #pragma unroll
    for (int dd = 0; dd < 64; dd += 4) {
        float4 kn0, kn1, kn2, kn3;
        if (dd + 4 < 64) {                 // compile-time after unroll
            const float* kp = kbase + (size_t)(dd + 4) * N_;
            kn0 = *(const float4*)(kp);
            kn1 = *(const float4*)(kp + N_);
            kn2 = *(const float4*)(kp + 2 * N_);
            kn3 = *(const float4*)(kp + 3 * N_);
        }
        ACC4(acc0, &s_q[0 * D_ + dlo + dd])
        ACC4(acc1, &s_q[1 * D_ + dlo + dd])
        ACC4(acc2, &s_q[2 * D_ + dlo + dd])
        ACC4(acc3, &s_q[3 * D_ + dlo + dd])
        kc0 = kn0; kc1 = kn1; kc2 = kn2; kc3 = kn3;
    }
#undef ACC4

    // ---- dump partials (one shot) ----
    *(float4*)&s_part[w * 1024 +   0 + lane * 4] = acc0;
    *(float4*)&s_part[w * 1024 + 256 + lane * 4] = acc1;
    *(float4*)&s_part[w * 1024 + 512 + lane * 4] = acc2;
    *(float4*)&s_part[w * 1024 + 768 + lane * 4] = acc3;
    __syncthreads();

    // ---- reduce 8 d-octants -> scores (1024 elems, 2 per thread) ----
    #pragma unroll
    for (int i = 0; i < 2; ++i) {
        const int e = t + 512 * i;      // 0..1023
        const int r = e >> 8;           // 0..3
        const int j = e & 255;
        const int sl = r * 256 + j;
        const float s = ((s_part[0 * 1024 + sl] + s_part[1 * 1024 + sl]) +
                         (s_part[2 * 1024 + sl] + s_part[3 * 1024 + sl])) +
                        ((s_part[4 * 1024 + sl] + s_part[5 * 1024 + sl]) +
                         (s_part[6 * 1024 + sl] + s_part[7 * 1024 + sl]));
        s_w[r * N_ + j] = -s;
    }
    __syncthreads();

    // ---- softmax: waves 0..3 handle rows 0..3 ----
    if (w < TI) {
        float* row = &s_w[w * N_];
        float v0 = row[lane];
        float v1 = row[lane + 64];
        float v2 = row[lane + 128];
        float v3 = row[lane + 192];
        float m = fmaxf(fmaxf(v0, v1), fmaxf(v2, v3));
        #pragma unroll
        for (int off = 32; off; off >>= 1) m = fmaxf(m, __shfl_xor(m, off));
        const float c = 1.4426950408889634f;
        float e0 = exp2f((v0 - m) * c);
        float e1 = exp2f((v1 - m) * c);
        float e2 = exp2f((v2 - m) * c);
        float e3 = exp2f((v3 - m) * c);
        float s = (e0 + e1) + (e2 + e3);
        #pragma unroll
        for (int off = 32; off; off >>= 1) s += __shfl_xor(s, off);
        const float r = 1.0f / s;
        row[lane]       = e0 * r;
        row[lane + 64]  = e1 * r;
        row[lane + 128] = e2 * r;
        row[lane + 192] = e3 * r;
    }
    __syncthreads();

    // ---- Phase C: out = attn @ v, all 4 rows per thread ----
    // thread: d-quad dq = t&127, j-quarter jq = t>>7 (64 j each)
    const int dq = t & 127;
    const int jq = t >> 7;
    const int j0 = jq * 64;
    const float* __restrict__ vb = v + (size_t)b * N_ * D_ + dq * 4;

    float4 a0 = make_float4(0.f,0.f,0.f,0.f);
    float4 a1 = make_float4(0.f,0.f,0.f,0.f);
    float4 a2 = make_float4(0.f,0.f,0.f,0.f);
    float4 a3 = make_float4(0.f,0.f,0.f,0.f);

    const float* vp0 = vb + (size_t)j0 * D_;
    float4 vc0 = *(const float4*)(vp0);
    float4 vc1 = *(const float4*)(vp0 + D_);
    float4 vc2 = *(const float4*)(vp0 + 2 * D_);
    float4 vc3 = *(const float4*)(vp0 + 3 * D_);

#define PVROW(A, W)                                                            \
    A.x += (W).x * vc0.x + (W).y * vc1.x + (W).z * vc2.x + (W).w * vc3.x;      \
    A.y += (W).x * vc0.y + (W).y * vc1.y + (W).z * vc2.y + (W).w * vc3.y;      \
    A.z += (W).x * vc0.z + (W).y * vc1.z + (W).z * vc2.z + (W).w * vc3.z;      \
    A.w += (W).x * vc0.w + (W).y * vc1.w + (W).z * vc2.w + (W).w * vc3.w;

    #pragma unroll
    for (int jo = 0; jo < 64; jo += 4) {
        float4 vn0, vn1, vn2, vn3;
        if (jo + 4 < 64) {
            const float* vpn = vb + (size_t)(j0 + jo + 4) * D_;
            vn0 = *(const float4*)(vpn);
            vn1 = *(const float4*)(vpn + D_);
            vn2 = *(const float4*)(vpn + 2 * D_);
            vn3 = *(const float4*)(vpn + 3 * D_);
        }
        const int j = j0 + jo;
        const float4 w0 = *(const float4*)&s_w[0 * N_ + j];
        const float4 w1 = *(const float4*)&s_w[1 * N_ + j];
        const float4 w2 = *(const float4*)&s_w[2 * N_ + j];
        const float4 w3 = *(const float4*)&s_w[3 * N_ + j];
        PVROW(a0, w0)
        PVROW(a1, w1)
        PVROW(a2, w2)
        PVROW(a3, w3)
        vc0 = vn0; vc1 = vn1; vc2 = vn2; vc3 = vn3;
    }
#undef PVROW

    __syncthreads();   // s_part reuse
    // layout: part[jq][r][d]: jq*2048 + r*512 + d
    *(float4*)&s_part[jq * 2048 + 0 * 512 + dq * 4] = a0;
    *(float4*)&s_part[jq * 2048 + 1 * 512 + dq * 4] = a1;
    *(float4*)&s_part[jq * 2048 + 2 * 512 + dq * 4] = a2;
    *(float4*)&s_part[jq * 2048 + 3 * 512 + dq * 4] = a3;
    __syncthreads();

    // ---- final: sum the 4 j-quarters, write out (1 float4 per thread) ----
    {
        const int r  = t >> 7;          // 0..3
        const int d4 = (t & 127) * 4;
        const float4 p0 = *(const float4*)&s_part[0 * 2048 + r * 512 + d4];
        const float4 p1 = *(const float4*)&s_part[1 * 2048 + r * 512 + d4];
        const float4 p2 = *(const float4*)&s_part[2 * 2048 + r * 512 + d4];
        const float4 p3 = *(const float4*)&s_part[3 * 2048 + r * 512 + d4];
        float4 s;
        s.x = (p0.x + p1.x) + (p2.x + p3.x);
        s.y = (p0.y + p1.y) + (p2.y + p3.y);
        s.z = (p0.z + p1.z) + (p2.z + p3.z);
        s.w = (p0.w + p1.w) + (p2.w + p3.w);
        *(float4*)(out + ((size_t)(b * N_ + i0 + r)) * D_ + d4) = s;
    }
}

// ---------- Fallback (round-1 kernel, used if ws too small) ----------
__global__ __launch_bounds__(256, 2)
void manh_attn_legacy(const float* __restrict__ q,
                      const float* __restrict__ k,
                      const float* __restrict__ v,
                      float* __restrict__ out)
{
    __shared__ float s_mat[4][N_];
    const int t   = threadIdx.x;
    const int bid = blockIdx.x;
    const int b   = bid >> 6;
    const int i0  = (bid & 63) * 4;

    const float* __restrict__ krow  = k + ((size_t)(b * N_ + t)) * D_;
    const float* __restrict__ qbase = q + ((size_t)(b * N_ + i0)) * D_;

    float acc0 = 0.f, acc1 = 0.f, acc2 = 0.f, acc3 = 0.f;
    #pragma unroll 4
    for (int d = 0; d < D_; d += 4) {
        const float4 kv = *(const float4*)(krow + d);
        const float4 q0 = *(const float4*)(qbase + d);
        const float4 q1 = *(const float4*)(qbase + D_ + d);
        const float4 q2 = *(const float4*)(qbase + 2 * D_ + d);
        const float4 q3 = *(const float4*)(qbase + 3 * D_ + d);
        acc0 += (fabsf(q0.x - kv.x) + fabsf(q0.y - kv.y)) + (fabsf(q0.z - kv.z) + fabsf(q0.w - kv.w));
        acc1 += (fabsf(q1.x - kv.x) + fabsf(q1.y - kv.y)) + (fabsf(q1.z - kv.z) + fabsf(q1.w - kv.w));
        acc2 += (fabsf(q2.x - kv.x) + fabsf(q2.y - kv.y)) + (fabsf(q2.z - kv.z) + fabsf(q2.w - kv.w));
        acc3 += (fabsf(q3.x - kv.x) + fabsf(q3.y - kv.y)) + (fabsf(q3.z - kv.z) + fabsf(q3.w - kv.w));
    }
    s_mat[0][t] = -acc0; s_mat[1][t] = -acc1; s_mat[2][t] = -acc2; s_mat[3][t] = -acc3;
    __syncthreads();
    {
        const int w = t >> 6;
        const int l = t & 63;
        float v0 = s_mat[w][l], v1 = s_mat[w][l + 64], v2 = s_mat[w][l + 128], v3 = s_mat[w][l + 192];
        float m = fmaxf(fmaxf(v0, v1), fmaxf(v2, v3));
        #pragma unroll
        for (int off = 32; off; off >>= 1) m = fmaxf(m, __shfl_xor(m, off));
        const float c = 1.4426950408889634f;
        float e0 = exp2f((v0 - m) * c), e1 = exp2f((v1 - m) * c);
        float e2 = exp2f((v2 - m) * c), e3 = exp2f((v3 - m) * c);
        float s = (e0 + e1) + (e2 + e3);
        #pragma unroll
        for (int off = 32; off; off >>= 1) s += __shfl_xor(s, off);
        const float r = 1.0f / s;
        s_mat[w][l] = e0 * r; s_mat[w][l + 64] = e1 * r;
        s_mat[w][l + 128] = e2 * r; s_mat[w][l + 192] = e3 * r;
    }
    __syncthreads();
    const int ig = t >> 7;
    const int d0 = (t & 127) * 4;
    const float* __restrict__ vbase = v + ((size_t)b * N_) * D_ + d0;
    const float* __restrict__ wr0 = &s_mat[2 * ig][0];
    const float* __restrict__ wr1 = &s_mat[2 * ig + 1][0];
    float4 a0 = make_float4(0.f, 0.f, 0.f, 0.f);
    float4 a1 = make_float4(0.f, 0.f, 0.f, 0.f);
#define PV_STEP(W0, W1, VV)                                     \
    a0.x += (W0) * (VV).x; a0.y += (W0) * (VV).y;               \
    a0.z += (W0) * (VV).z; a0.w += (W0) * (VV).w;               \
    a1.x += (W1) * (VV).x; a1.y += (W1) * (VV).y;               \
    a1.z += (W1) * (VV).z; a1.w += (W1) * (VV).w;
    #pragma unroll 2
    for (int j = 0; j < N_; j += 4) {
        const float4 w0 = *(const float4*)(wr0 + j);
        const float4 w1 = *(const float4*)(wr1 + j);
        const float4 vv0 = *(const float4*)(vbase + (size_t)(j + 0) * D_);
        const float4 vv1 = *(const float4*)(vbase + (size_t)(j + 1) * D_);
        const float4 vv2 = *(const float4*)(vbase + (size_t)(j + 2) * D_);
        const float4 vv3 = *(const float4*)(vbase + (size_t)(j + 3) * D_);
        PV_STEP(w0.x, w1.x, vv0)
        PV_STEP(w0.y, w1.y, vv1)
        PV_STEP(w0.z, w1.z, vv2)
        PV_STEP(w0.w, w1.w, vv3)
    }
#undef PV_STEP
    float* op = out + ((size_t)(b * N_ + i0 + 2 * ig)) * D_ + d0;
    *(float4*)op        = a0;
    *(float4*)(op + D_) = a1;
}

extern "C" void kernel_launch(void* const* d_in, const int* in_sizes, int n_in,
                              void* d_out, int out_size, void* d_ws, size_t ws_size,
                              hipStream_t stream)
{
    const float* q = (const float*)d_in[0];
    const float* k = (const float*)d_in[1];
    const float* v = (const float*)d_in[2];
    float* out = (float*)d_out;

    const size_t kT_bytes = (size_t)B_ * N_ * D_ * sizeof(float);
    if (ws_size >= kT_bytes) {
        float* kT = (float*)d_ws;
        transpose_k<<<dim3(D_ / 32, N_ / 32, B_), dim3(32, 8), 0, stream>>>(k, kT);
        manh_attn_v6<<<dim3(B_ * (N_ / TI)), dim3(512), 0, stream>>>(q, kT, v, out);
    } else {
        manh_attn_legacy<<<dim3(B_ * 64), dim3(256), 0, stream>>>(q, k, v, out);
    }
}

// Round 7
// 43.795 us; speedup vs baseline: 8.0994x; 8.0994x over previous
//
#include <hip/hip_runtime.h>

#define B_ 8
#define N_ 256
#define D_ 512
#define TI 4   // query rows per block

// ---------- Kernel 0: transpose k[b][j][d] -> kT[b][d][j] ----------
__global__ __launch_bounds__(256)
void transpose_k(const float* __restrict__ k, float* __restrict__ kT)
{
    __shared__ float tile[32][33];
    const int dt = blockIdx.x * 32;
    const int jt = blockIdx.y * 32;
    const int b  = blockIdx.z;
    const int tx = threadIdx.x;   // 0..31
    const int ty = threadIdx.y;   // 0..7

    const float* __restrict__ src = k  + ((size_t)b * N_) * D_;
    float* __restrict__       dst = kT + ((size_t)b * D_) * N_;

    #pragma unroll
    for (int r = 0; r < 4; ++r) {
        const int jj = ty * 4 + r;
        tile[jj][tx] = src[(size_t)(jt + jj) * D_ + dt + tx];
    }
    __syncthreads();
    #pragma unroll
    for (int r = 0; r < 4; ++r) {
        const int dd = ty * 4 + r;
        dst[(size_t)(dt + dd) * N_ + jt + tx] = tile[tx][dd];
    }
}

// async 16B global -> LDS (fire-and-forget, completes at s_waitcnt vmcnt)
__device__ __forceinline__ void load_lds_16B(const float* g, float* l)
{
    __builtin_amdgcn_global_load_lds(
        (const __attribute__((address_space(1))) void*)g,
        (__attribute__((address_space(3))) void*)l, 16, 0, 0);
}

// ---------- Main kernel: TI=4, 512 threads (8 waves), grid = 512 ----------
// b = bid & 7 (batch-major XCD mapping), tile = bid >> 3.
// Phase A: k staged via global_load_lds, double-buffered 16-d chunks.
//          Wave w owns chunk-d's {2w, 2w+1}; lane owns j-quad.
// Phase C: thread owns (d-quad, j-quarter) x all 4 rows; v read exactly once.
__global__ __launch_bounds__(512, 4)
void manh_attn_v7(const float* __restrict__ q,
                  const float* __restrict__ kT,
                  const float* __restrict__ v,
                  float* __restrict__ out)
{
    __shared__ float s_q[TI * D_];       // 8 KB
    __shared__ float s_kbuf[2][4096];    // 32 KB: k-chunk dbuf; later reduce scratch
    __shared__ float s_w[TI * N_];       // 4 KB

    float* s_part = &s_kbuf[0][0];       // 8192-float scratch alias

    const int t  = threadIdx.x;
    const int b  = blockIdx.x & 7;          // batch -> XCD locality
    const int i0 = (blockIdx.x >> 3) * TI;  // 0..63 tiles

    const float* __restrict__ kTb = kT + (size_t)b * D_ * N_;

    // ---- stage q tile (coalesced float4) + chunk 0 of k ----
    {
        const float* __restrict__ qsrc = q + ((size_t)(b * N_ + i0)) * D_;
        *(float4*)&s_q[4 * t] = *(const float4*)(qsrc + 4 * t);
        load_lds_16B(kTb + 4 * t,        &s_kbuf[0][4 * t]);
        load_lds_16B(kTb + 2048 + 4 * t, &s_kbuf[0][2048 + 4 * t]);
    }
    __syncthreads();   // drains vmcnt -> chunk 0 resident

    const int lane = t & 63;
    const int w    = t >> 6;       // 0..7
    const int jq   = lane;         // j-quad: j = jq*4 .. +3

    // ---- Phase A: L1 distances, 32 chunks of 16 d ----
    float4 acc0 = make_float4(0.f,0.f,0.f,0.f);
    float4 acc1 = make_float4(0.f,0.f,0.f,0.f);
    float4 acc2 = make_float4(0.f,0.f,0.f,0.f);
    float4 acc3 = make_float4(0.f,0.f,0.f,0.f);

    for (int c = 0; c < 32; ++c) {
        const int buf = c & 1;
        // issue async stage of chunk c+1 into the other buffer
        if (c < 31) {
            const float* src = kTb + (size_t)(c + 1) * 4096;
            load_lds_16B(src + 4 * t,        &s_kbuf[buf ^ 1][4 * t]);
            load_lds_16B(src + 2048 + 4 * t, &s_kbuf[buf ^ 1][2048 + 4 * t]);
        }
        // compute chunk c: wave w -> d_local {2w, 2w+1}
        const float4 k0 = *(const float4*)&s_kbuf[buf][(2 * w + 0) * 256 + jq * 4];
        const float4 k1 = *(const float4*)&s_kbuf[buf][(2 * w + 1) * 256 + jq * 4];
        const int dbase = c * 16 + 2 * w;
        const float2 q20 = *(const float2*)&s_q[0 * D_ + dbase];
        const float2 q21 = *(const float2*)&s_q[1 * D_ + dbase];
        const float2 q22 = *(const float2*)&s_q[2 * D_ + dbase];
        const float2 q23 = *(const float2*)&s_q[3 * D_ + dbase];

#define ACC2(A, Q2)                                             \
        A.x += fabsf((Q2).x - k0.x) + fabsf((Q2).y - k1.x);     \
        A.y += fabsf((Q2).x - k0.y) + fabsf((Q2).y - k1.y);     \
        A.z += fabsf((Q2).x - k0.z) + fabsf((Q2).y - k1.z);     \
        A.w += fabsf((Q2).x - k0.w) + fabsf((Q2).y - k1.w);
        ACC2(acc0, q20)
        ACC2(acc1, q21)
        ACC2(acc2, q22)
        ACC2(acc3, q23)
#undef ACC2
        __syncthreads();   // drains chunk c+1 loads; protects buf overwrite
    }

    // ---- dump partials into s_part (s_kbuf free now) ----
    *(float4*)&s_part[w * 1024 + 0 * 256 + jq * 4] = acc0;
    *(float4*)&s_part[w * 1024 + 1 * 256 + jq * 4] = acc1;
    *(float4*)&s_part[w * 1024 + 2 * 256 + jq * 4] = acc2;
    *(float4*)&s_part[w * 1024 + 3 * 256 + jq * 4] = acc3;
    __syncthreads();

    // ---- reduce 8 wave-partials -> scores ----
    #pragma unroll
    for (int i = 0; i < 2; ++i) {
        const int e = t + 512 * i;      // 0..1023
        const int r = e >> 8;           // 0..3
        const int j = e & 255;
        const int sl = r * 256 + j;
        const float s = ((s_part[0 * 1024 + sl] + s_part[1 * 1024 + sl]) +
                         (s_part[2 * 1024 + sl] + s_part[3 * 1024 + sl])) +
                        ((s_part[4 * 1024 + sl] + s_part[5 * 1024 + sl]) +
                         (s_part[6 * 1024 + sl] + s_part[7 * 1024 + sl]));
        s_w[r * N_ + j] = -s;
    }
    __syncthreads();

    // ---- softmax: waves 0..3 handle rows 0..3 ----
    if (w < TI) {
        float* row = &s_w[w * N_];
        float v0 = row[lane];
        float v1 = row[lane + 64];
        float v2 = row[lane + 128];
        float v3 = row[lane + 192];
        float m = fmaxf(fmaxf(v0, v1), fmaxf(v2, v3));
        #pragma unroll
        for (int off = 32; off; off >>= 1) m = fmaxf(m, __shfl_xor(m, off));
        const float c = 1.4426950408889634f;
        float e0 = exp2f((v0 - m) * c);
        float e1 = exp2f((v1 - m) * c);
        float e2 = exp2f((v2 - m) * c);
        float e3 = exp2f((v3 - m) * c);
        float s = (e0 + e1) + (e2 + e3);
        #pragma unroll
        for (int off = 32; off; off >>= 1) s += __shfl_xor(s, off);
        const float r = 1.0f / s;
        row[lane]       = e0 * r;
        row[lane + 64]  = e1 * r;
        row[lane + 128] = e2 * r;
        row[lane + 192] = e3 * r;
    }
    __syncthreads();

    // ---- Phase C: out = attn @ v, all 4 rows per thread, v read once ----
    // thread: d-quad dq = t&127, j-quarter jq4 = t>>7 (64 j each)
    const int dq  = t & 127;
    const int jq4 = t >> 7;
    const int j0  = jq4 * 64;
    const float* __restrict__ vb = v + (size_t)b * N_ * D_ + dq * 4;

    float4 a0 = make_float4(0.f,0.f,0.f,0.f);
    float4 a1 = make_float4(0.f,0.f,0.f,0.f);
    float4 a2 = make_float4(0.f,0.f,0.f,0.f);
    float4 a3 = make_float4(0.f,0.f,0.f,0.f);

#define PVROW(A, W)                                                            \
    A.x += (W).x * vv0.x + (W).y * vv1.x + (W).z * vv2.x + (W).w * vv3.x;      \
    A.y += (W).x * vv0.y + (W).y * vv1.y + (W).z * vv2.y + (W).w * vv3.y;      \
    A.z += (W).x * vv0.z + (W).y * vv1.z + (W).z * vv2.z + (W).w * vv3.z;      \
    A.w += (W).x * vv0.w + (W).y * vv1.w + (W).z * vv2.w + (W).w * vv3.w;

    #pragma unroll 2
    for (int jo = 0; jo < 64; jo += 4) {
        const int j = j0 + jo;
        const float4 vv0 = *(const float4*)(vb + (size_t)(j + 0) * D_);
        const float4 vv1 = *(const float4*)(vb + (size_t)(j + 1) * D_);
        const float4 vv2 = *(const float4*)(vb + (size_t)(j + 2) * D_);
        const float4 vv3 = *(const float4*)(vb + (size_t)(j + 3) * D_);
        const float4 w0 = *(const float4*)&s_w[0 * N_ + j];
        const float4 w1 = *(const float4*)&s_w[1 * N_ + j];
        const float4 w2 = *(const float4*)&s_w[2 * N_ + j];
        const float4 w3 = *(const float4*)&s_w[3 * N_ + j];
        PVROW(a0, w0)
        PVROW(a1, w1)
        PVROW(a2, w2)
        PVROW(a3, w3)
    }
#undef PVROW

    // ---- reduce 4 j-quarters via s_part (no conflict with s_w) ----
    *(float4*)&s_part[jq4 * 2048 + 0 * 512 + dq * 4] = a0;
    *(float4*)&s_part[jq4 * 2048 + 1 * 512 + dq * 4] = a1;
    *(float4*)&s_part[jq4 * 2048 + 2 * 512 + dq * 4] = a2;
    *(float4*)&s_part[jq4 * 2048 + 3 * 512 + dq * 4] = a3;
    __syncthreads();

    {
        const int r  = t >> 7;          // 0..3
        const int d4 = (t & 127) * 4;
        const float4 p0 = *(const float4*)&s_part[0 * 2048 + r * 512 + d4];
        const float4 p1 = *(const float4*)&s_part[1 * 2048 + r * 512 + d4];
        const float4 p2 = *(const float4*)&s_part[2 * 2048 + r * 512 + d4];
        const float4 p3 = *(const float4*)&s_part[3 * 2048 + r * 512 + d4];
        float4 s;
        s.x = (p0.x + p1.x) + (p2.x + p3.x);
        s.y = (p0.y + p1.y) + (p2.y + p3.y);
        s.z = (p0.z + p1.z) + (p2.z + p3.z);
        s.w = (p0.w + p1.w) + (p2.w + p3.w);
        *(float4*)(out + ((size_t)(b * N_ + i0 + r)) * D_ + d4) = s;
    }
}

// ---------- Fallback (round-1 kernel, used if ws too small) ----------
__global__ __launch_bounds__(256, 2)
void manh_attn_legacy(const float* __restrict__ q,
                      const float* __restrict__ k,
                      const float* __restrict__ v,
                      float* __restrict__ out)
{
    __shared__ float s_mat[4][N_];
    const int t   = threadIdx.x;
    const int bid = blockIdx.x;
    const int b   = bid >> 6;
    const int i0  = (bid & 63) * 4;

    const float* __restrict__ krow  = k + ((size_t)(b * N_ + t)) * D_;
    const float* __restrict__ qbase = q + ((size_t)(b * N_ + i0)) * D_;

    float acc0 = 0.f, acc1 = 0.f, acc2 = 0.f, acc3 = 0.f;
    #pragma unroll 4
    for (int d = 0; d < D_; d += 4) {
        const float4 kv = *(const float4*)(krow + d);
        const float4 q0 = *(const float4*)(qbase + d);
        const float4 q1 = *(const float4*)(qbase + D_ + d);
        const float4 q2 = *(const float4*)(qbase + 2 * D_ + d);
        const float4 q3 = *(const float4*)(qbase + 3 * D_ + d);
        acc0 += (fabsf(q0.x - kv.x) + fabsf(q0.y - kv.y)) + (fabsf(q0.z - kv.z) + fabsf(q0.w - kv.w));
        acc1 += (fabsf(q1.x - kv.x) + fabsf(q1.y - kv.y)) + (fabsf(q1.z - kv.z) + fabsf(q1.w - kv.w));
        acc2 += (fabsf(q2.x - kv.x) + fabsf(q2.y - kv.y)) + (fabsf(q2.z - kv.z) + fabsf(q2.w - kv.w));
        acc3 += (fabsf(q3.x - kv.x) + fabsf(q3.y - kv.y)) + (fabsf(q3.z - kv.z) + fabsf(q3.w - kv.w));
    }
    s_mat[0][t] = -acc0; s_mat[1][t] = -acc1; s_mat[2][t] = -acc2; s_mat[3][t] = -acc3;
    __syncthreads();
    {
        const int w = t >> 6;
        const int l = t & 63;
        float v0 = s_mat[w][l], v1 = s_mat[w][l + 64], v2 = s_mat[w][l + 128], v3 = s_mat[w][l + 192];
        float m = fmaxf(fmaxf(v0, v1), fmaxf(v2, v3));
        #pragma unroll
        for (int off = 32; off; off >>= 1) m = fmaxf(m, __shfl_xor(m, off));
        const float c = 1.4426950408889634f;
        float e0 = exp2f((v0 - m) * c), e1 = exp2f((v1 - m) * c);
        float e2 = exp2f((v2 - m) * c), e3 = exp2f((v3 - m) * c);
        float s = (e0 + e1) + (e2 + e3);
        #pragma unroll
        for (int off = 32; off; off >>= 1) s += __shfl_xor(s, off);
        const float r = 1.0f / s;
        s_mat[w][l] = e0 * r; s_mat[w][l + 64] = e1 * r;
        s_mat[w][l + 128] = e2 * r; s_mat[w][l + 192] = e3 * r;
    }
    __syncthreads();
    const int ig = t >> 7;
    const int d0 = (t & 127) * 4;
    const float* __restrict__ vbase = v + ((size_t)b * N_) * D_ + d0;
    const float* __restrict__ wr0 = &s_mat[2 * ig][0];
    const float* __restrict__ wr1 = &s_mat[2 * ig + 1][0];
    float4 a0 = make_float4(0.f, 0.f, 0.f, 0.f);
    float4 a1 = make_float4(0.f, 0.f, 0.f, 0.f);
#define PV_STEP(W0, W1, VV)                                     \
    a0.x += (W0) * (VV).x; a0.y += (W0) * (VV).y;               \
    a0.z += (W0) * (VV).z; a0.w += (W0) * (VV).w;               \
    a1.x += (W1) * (VV).x; a1.y += (W1) * (VV).y;               \
    a1.z += (W1) * (VV).z; a1.w += (W1) * (VV).w;
    #pragma unroll 2
    for (int j = 0; j < N_; j += 4) {
        const float4 w0 = *(const float4*)(wr0 + j);
        const float4 w1 = *(const float4*)(wr1 + j);
        const float4 vv0 = *(const float4*)(vbase + (size_t)(j + 0) * D_);
        const float4 vv1 = *(const float4*)(vbase + (size_t)(j + 1) * D_);
        const float4 vv2 = *(const float4*)(vbase + (size_t)(j + 2) * D_);
        const float4 vv3 = *(const float4*)(vbase + (size_t)(j + 3) * D_);
        PV_STEP(w0.x, w1.x, vv0)
        PV_STEP(w0.y, w1.y, vv1)
        PV_STEP(w0.z, w1.z, vv2)
        PV_STEP(w0.w, w1.w, vv3)
    }
#undef PV_STEP
    float* op = out + ((size_t)(b * N_ + i0 + 2 * ig)) * D_ + d0;
    *(float4*)op        = a0;
    *(float4*)(op + D_) = a1;
}

extern "C" void kernel_launch(void* const* d_in, const int* in_sizes, int n_in,
                              void* d_out, int out_size, void* d_ws, size_t ws_size,
                              hipStream_t stream)
{
    const float* q = (const float*)d_in[0];
    const float* k = (const float*)d_in[1];
    const float* v = (const float*)d_in[2];
    float* out = (float*)d_out;

    const size_t kT_bytes = (size_t)B_ * N_ * D_ * sizeof(float);
    if (ws_size >= kT_bytes) {
        float* kT = (float*)d_ws;
        transpose_k<<<dim3(D_ / 32, N_ / 32, B_), dim3(32, 8), 0, stream>>>(k, kT);
        manh_attn_v7<<<dim3(B_ * (N_ / TI)), dim3(512), 0, stream>>>(q, kT, v, out);
    } else {
        manh_attn_legacy<<<dim3(B_ * 64), dim3(256), 0, stream>>>(q, k, v, out);
    }
}